// Round 16
// baseline (4548.964 us; speedup 1.0000x reference)
//
#include <hip/hip_runtime.h>
#include <stdint.h>

typedef __attribute__((ext_vector_type(8))) short short8;
typedef __attribute__((ext_vector_type(4))) float f32x4;
typedef __attribute__((ext_vector_type(4))) unsigned short u16x4;

// Problem constants: T=512, B=64, D=768, H=768, 4H=3072
#define NWG 96

// ws layout (bytes, all 256-aligned)
#define OFF_XBF   0UL
#define SZ_XBF    (512UL*64*768*2)      // xb; REUSED as 512 per-t h buffers
#define OFF_WXB   (OFF_XBF + SZ_XBF)
#define SZ_WB     (3072UL*768*2)        // Wxb; REUSED as per-t flags
#define OFF_WHB   (OFF_WXB + SZ_WB)
#define OFF_BALL  (OFF_WHB + SZ_WB)
#define SZ_BALL   (3072UL*4)
#define OFF_XG    (OFF_BALL + SZ_BALL)
#define SZ_XG     (512UL*3072*64*2)
#define OFF_END   (OFF_XG + SZ_XG)

// per-t h buffer: 64x768 bf16 = 98304 B; 512 of them = SZ_XBF exactly.
#define HSTRIDE   49152               // shorts per h buffer
// per-t flags: 96 x 64B = 6144 B (1536 ints); 512 steps = 3.1 MB < SZ_WB.
#define FSTRIDE   1536                // ints per step

__device__ __forceinline__ float bf2f(unsigned short u){
  union{unsigned int i; float f;} v; v.i = ((unsigned int)u)<<16; return v.f;
}
__device__ __forceinline__ unsigned short f2bf(float f){
  union{float f; unsigned int i;} v; v.f = f;
  unsigned int x = v.i;
  return (unsigned short)((x + 0x7fffu + ((x>>16)&1u)) >> 16);
}
__device__ __forceinline__ float sigm(float x){ return 1.0f/(1.0f + __expf(-x)); }
// overflow-safe tanh
__device__ __forceinline__ float tanh_s(float x){
  float e = __expf(2.0f*fabsf(x));
  float r = 1.0f - 2.0f/(e+1.0f);
  return copysignf(r, x);
}
__device__ __forceinline__ f32x4 mfma16(short8 a, short8 b, f32x4 c){
  return __builtin_amdgcn_mfma_f32_16x16x32_bf16(a, b, c, 0, 0, 0);
}
// h producer stores bypass L1+L2 (reach the memory-side coherence point, no
// dirty local-L2 copies). Readers use PLAIN cached loads on per-t addresses:
// never-reused addresses can't be stale in any cache. (Round-8, PASSED.)
__device__ __forceinline__ void st_b128_sc(unsigned short* p, short8 v){
  asm volatile("global_store_dwordx4 %0, %1, off sc0 sc1"
               :: "v"(p), "v"(v) : "memory");
}

// ---- converters ----
__global__ void k_conv_x(const float* __restrict__ x, unsigned short* __restrict__ xb, int n4){
  int i = blockIdx.x*blockDim.x + threadIdx.x;
  if (i >= n4) return;
  float4 v = ((const float4*)x)[i];
  u16x4 o = { f2bf(v.x), f2bf(v.y), f2bf(v.z), f2bf(v.w) };
  *(u16x4*)(xb + (size_t)i*4) = o;
}

__global__ void k_conv_w(const float* __restrict__ Wf, const float* __restrict__ Wi,
                         const float* __restrict__ Wg, const float* __restrict__ Wo,
                         unsigned short* __restrict__ Wxb, unsigned short* __restrict__ Whb){
  int i = blockIdx.x*blockDim.x + threadIdx.x;
  if (i >= 3072*192) return;
  int gj = i / 192; int kc = (i % 192)*4;
  int g = gj / 768, j = gj % 768;
  const float* W = (g==0)?Wf:(g==1)?Wi:(g==2)?Wg:Wo;
  float4 vx = *(const float4*)(W + (size_t)j*1536 + kc);
  float4 vh = *(const float4*)(W + (size_t)j*1536 + 768 + kc);
  u16x4 ox = {f2bf(vx.x),f2bf(vx.y),f2bf(vx.z),f2bf(vx.w)};
  u16x4 oh = {f2bf(vh.x),f2bf(vh.y),f2bf(vh.z),f2bf(vh.w)};
  *(u16x4*)(Wxb + (size_t)gj*768 + kc) = ox;
  *(u16x4*)(Whb + (size_t)gj*768 + kc) = oh;
}

__global__ void k_conv_b(const float* __restrict__ b0, const float* __restrict__ b1,
                         const float* __restrict__ b2, const float* __restrict__ b3,
                         float* __restrict__ ball){
  int i = blockIdx.x*blockDim.x + threadIdx.x;
  if (i >= 3072) return;
  int g = i/768, j = i%768;
  const float* b = (g==0)?b0:(g==1)?b1:(g==2)?b2:b3;
  ball[i] = b[j];
}

// ---- phase 1: Xg[t][gj][b] = (x @ Wx^T) + bias  (bias folded in) ----
__global__ __launch_bounds__(256) void k_gemm_x(const unsigned short* __restrict__ xb,
        const unsigned short* __restrict__ Wxb, const float* __restrict__ ball,
        unsigned short* __restrict__ Xg){
  __shared__ __align__(16) short Ald[128*32];
  __shared__ __align__(16) short Bld[128*32];
  int blk = blockIdx.x;
  int bm = blk / 24, bn = blk % 24;
  size_t Mbase = (size_t)bm*128; int Nbase = bn*128;
  int tid = threadIdx.x; int w = tid>>6, l = tid&63;
  int wm = w&1, wn = w>>1, lr = l&15, lg = l>>4;
  f32x4 acc[4][4];
  #pragma unroll
  for (int a=0;a<4;++a)
    #pragma unroll
    for(int b2=0;b2<4;++b2) acc[a][b2] = (f32x4){0.f,0.f,0.f,0.f};
  int c0i = tid, c1i = tid+256;
  int r0 = c0i>>2, o0 = (c0i&3)*8;
  int r1 = c1i>>2, o1 = (c1i&3)*8;
  for (int kt=0; kt<24; ++kt) {
    int k0 = kt*32;
    short8 a0 = *(const short8*)(xb + (Mbase + r0)*768 + k0 + o0);
    short8 a1 = *(const short8*)(xb + (Mbase + r1)*768 + k0 + o1);
    short8 b0 = *(const short8*)(Wxb + (size_t)(Nbase + r0)*768 + k0 + o0);
    short8 b1 = *(const short8*)(Wxb + (size_t)(Nbase + r1)*768 + k0 + o1);
    __syncthreads();
    *(short8*)(Ald + r0*32 + o0) = a0;
    *(short8*)(Ald + r1*32 + o1) = a1;
    *(short8*)(Bld + r0*32 + o0) = b0;
    *(short8*)(Bld + r1*32 + o1) = b1;
    __syncthreads();
    short8 af[4], bfr[4];
    #pragma unroll
    for (int mi=0;mi<4;++mi) af[mi] = *(const short8*)(Ald + (wm*64+mi*16+lr)*32 + lg*8);
    #pragma unroll
    for (int ni=0;ni<4;++ni) bfr[ni] = *(const short8*)(Bld + (wn*64+ni*16+lr)*32 + lg*8);
    #pragma unroll
    for (int mi=0;mi<4;++mi)
      #pragma unroll
      for (int ni=0;ni<4;++ni)
        acc[mi][ni] = mfma16(af[mi], bfr[ni], acc[mi][ni]);
  }
  float bs[4];
  #pragma unroll
  for (int ni=0;ni<4;++ni) bs[ni] = ball[Nbase + wn*64 + ni*16 + lr];
  #pragma unroll
  for (int mi=0;mi<4;++mi){
    int m0 = (int)Mbase + wm*64 + mi*16 + lg*4;
    int t = m0>>6, b = m0&63;
    #pragma unroll
    for (int ni=0;ni<4;++ni){
      int col = Nbase + wn*64 + ni*16 + lr;
      u16x4 u = { f2bf(acc[mi][ni][0]+bs[ni]), f2bf(acc[mi][ni][1]+bs[ni]),
                  f2bf(acc[mi][ni][2]+bs[ni]), f2bf(acc[mi][ni][3]+bs[ni]) };
      *(u16x4*)(Xg + ((size_t)t*3072 + col)*64 + b) = u;
    }
  }
}

// ---- phase 2: persistent recurrent kernel (ROUND-8 FRAME, passed on HW).
// 96 WGs x 512 thr. Per-t h buffers (addresses never reused -> plain cached
// consumer loads are staleness-free). Producer: wave-7 packed sc0|sc1 stores
// + own-wave vmcnt drain + per-t relaxed agent flag. Wave-0 polls, WG-wide
// syncthreads release. Deltas vs round 8: bias pre-folded into Xg; `out`
// stores DEFERRED one step (off the pre-barrier critical path); sleep-free
// bounded poll.
__global__ __launch_bounds__(512, 1) void k_lstm(const unsigned short* __restrict__ Xg,
     const unsigned short* __restrict__ Whb,
     unsigned short* __restrict__ hbase, float* __restrict__ out,
     int* __restrict__ flags){
  __shared__ __align__(16) short Wl[32*776];          // Wh slice (2-way bank alias only)
  __shared__ __align__(16) unsigned short hl[64*8];   // h pack tile
  int s = blockIdx.x, tid = threadIdx.x;
  int w8 = tid>>6, l = tid&63;
  int m = w8 & 3, nh = w8 >> 2;
  int n0 = l & 15, lg = l >> 4;
  int gate = n0 >> 2;
  int jj4 = nh*4 + (n0 & 3);
  int j = s*8 + jj4;
  size_t gj = (size_t)gate*768 + j;
  int rB = jj4*4 + gate;

  // stage Wh slice once: Wl[rB][k] = Whb[gate*768 + s*8 + jj][k]
  for (int c = tid; c < 3072; c += 512){
    int r = c/96, off = (c%96)*8;
    int gt = r & 3, jq = r >> 2;
    short8 v = *(const short8*)(Whb + ((size_t)(gt*768 + s*8 + jq))*768 + off);
    *(short8*)(Wl + r*776 + off) = v;
  }
  __syncthreads();

  float cst[4] = {0.f, 0.f, 0.f, 0.f};
  int arow = m*16 + n0;
  int b4 = m*16 + lg*4;
  bool actv = (n0 < 4);
  u16x4 xg = *(const u16x4*)(Xg + gj*64 + b4);   // t=0 prefetch
  float pend[4];                                  // deferred out values

  for (int t=0; t<512; ++t){
    const unsigned short* hb = hbase + (size_t)t*HSTRIDE;
    unsigned short* hn = hbase + (size_t)(t+1)*HSTRIDE;
    // deferred out stores for step t-1 (post-release; hidden under A-loads)
    if (t > 0 && actv){
      #pragma unroll
      for (int r=0;r<4;++r)
        out[((size_t)(t-1)*64 + b4 + r)*768 + j] = pend[r];
    }
    // A-fragments (h_t): plain cached loads on fresh per-t addresses
    short8 afr[24];
    #pragma unroll
    for (int kk=0; kk<24; ++kk)
      afr[kk] = *(const short8*)(hb + arow*768 + kk*32 + lg*8);
    // MFMA with B from LDS; two acc chains for latency
    f32x4 acc0 = {0.f,0.f,0.f,0.f}, acc1 = {0.f,0.f,0.f,0.f};
    #pragma unroll
    for (int kk=0; kk<24; kk+=2){
      short8 b0 = *(const short8*)(Wl + rB*776 + kk*32 + lg*8);
      short8 b1 = *(const short8*)(Wl + rB*776 + (kk+1)*32 + lg*8);
      acc0 = mfma16(afr[kk],   b0, acc0);
      acc1 = mfma16(afr[kk+1], b1, acc1);
    }
    f32x4 acc = acc0 + acc1;
    // pre-activation (bias already folded into Xg) + gate nonlinearity
    float av[4];
    #pragma unroll
    for (int r=0; r<4; ++r){
      float pre = acc[r] + bf2f(xg[r]);
      av[r] = (gate == 2) ? tanh_s(pre) : sigm(pre);
    }
    // gather i (xor4), g (xor8), o (xor12); f lane-local for n0<4
    #pragma unroll
    for (int r=0; r<4; ++r){
      float iv = __shfl_xor(av[r], 4);
      float gv = __shfl_xor(av[r], 8);
      float ov = __shfl_xor(av[r], 12);
      float cn = av[r]*cst[r] + iv*gv;
      float hv = ov * tanh_s(cn);
      if (actv){
        cst[r] = cn;
        pend[r] = hv;
        hl[(b4 + r)*8 + jj4] = f2bf(hv);   // pack tile
      }
    }
    if (t < 511){
      __syncthreads();                   // hl complete
      if (w8 == 7){
        // 64 coalesced 16B h-stores to h[t+1]; only these gate the flag
        short8 hp = *(const short8*)(hl + l*8);
        st_b128_sc(hn + (size_t)l*768 + s*8, hp);
        asm volatile("s_waitcnt vmcnt(0)" ::: "memory");
        if (l == 0)
          __hip_atomic_store(&flags[(size_t)t*FSTRIDE + s*16], 1,
                             __ATOMIC_RELAXED, __HIP_MEMORY_SCOPE_AGENT);
      }
      u16x4 xgn = *(const u16x4*)(Xg + ((size_t)(t+1)*3072 + gj)*64 + b4);
      if (w8 == 0){
        const int* fl = flags + (size_t)t*FSTRIDE;
        // sleep-free bounded spin (wave 0 only); bound -> wrong, not hang
        for (int it=0; it<(1<<15); ++it){
          int f1 = __hip_atomic_load(&fl[l*16], __ATOMIC_RELAXED, __HIP_MEMORY_SCOPE_AGENT);
          int f2 = (l<32) ? __hip_atomic_load(&fl[(64+l)*16], __ATOMIC_RELAXED, __HIP_MEMORY_SCOPE_AGENT) : 1;
          if (__all(f1!=0 && f2!=0)) break;
        }
      }
      __syncthreads();                   // release: all 96 flags set for t
      xg = xgn;
    }
  }
  // final stores: out[511] + hT + cT
  if (actv){
    #pragma unroll
    for (int r=0; r<4; ++r){
      int b = b4 + r;
      out[((size_t)511*64 + b)*768 + j] = pend[r];
      out[(512UL*64 + b)*768 + j] = pend[r];      // hT
      out[(512UL*64 + 64 + b)*768 + j] = cst[r];  // cT
    }
  }
}

extern "C" void kernel_launch(void* const* d_in, const int* in_sizes, int n_in,
                              void* d_out, int out_size, void* d_ws, size_t ws_size,
                              hipStream_t stream){
  const float* x   = (const float*)d_in[0];
  const float* Wf  = (const float*)d_in[1];
  const float* bf_ = (const float*)d_in[2];
  const float* Wi  = (const float*)d_in[3];
  const float* bi_ = (const float*)d_in[4];
  const float* Wg  = (const float*)d_in[5];
  const float* bg_ = (const float*)d_in[6];
  const float* Wo  = (const float*)d_in[7];
  const float* bo_ = (const float*)d_in[8];
  char* ws = (char*)d_ws;
  if (ws_size < OFF_END) return;  // need ~252 MB scratch
  unsigned short* xb   = (unsigned short*)(ws + OFF_XBF);   // then: per-t h buffers
  unsigned short* Wxb  = (unsigned short*)(ws + OFF_WXB);   // then: per-t flags
  unsigned short* Whb  = (unsigned short*)(ws + OFF_WHB);
  float*          ball = (float*)(ws + OFF_BALL);
  unsigned short* Xg   = (unsigned short*)(ws + OFF_XG);
  float* out = (float*)d_out;

  k_conv_x<<<24576, 256, 0, stream>>>(x, xb, 6291456);
  k_conv_w<<<2304, 256, 0, stream>>>(Wf, Wi, Wg, Wo, Wxb, Whb);
  k_conv_b<<<12, 256, 0, stream>>>(bf_, bi_, bg_, bo_, ball);
  k_gemm_x<<<6144, 256, 0, stream>>>(xb, Wxb, ball, Xg);
  // xb/Wxb are dead now; reuse as per-t h buffers (h0=0) and per-t flags=0.
  // (MUST be after k_gemm_x in stream order; reset every call for replays.)
  (void)hipMemsetAsync(ws + OFF_XBF, 0, 98304, stream);            // h[0] = 0
  (void)hipMemsetAsync(ws + OFF_WXB, 0, 512UL*FSTRIDE*4, stream);  // flags = 0
  k_lstm<<<NWG, 512, 0, stream>>>(Xg, Whb,
                                  (unsigned short*)(ws + OFF_XBF), out,
                                  (int*)(ws + OFF_WXB));
}

// Round 18
// 4500.256 us; speedup vs baseline: 1.0108x; 1.0108x over previous
//
#include <hip/hip_runtime.h>
#include <stdint.h>

typedef __attribute__((ext_vector_type(8))) short short8;
typedef __attribute__((ext_vector_type(4))) float f32x4;
typedef __attribute__((ext_vector_type(4))) unsigned short u16x4;

// Problem constants: T=512, B=64, D=768, H=768, 4H=3072
#define NWG 96

// ws layout (bytes, all 256-aligned)
#define OFF_XBF   0UL
#define SZ_XBF    (512UL*64*768*2)      // xb; REUSED as 512 per-t h buffers
#define OFF_WXB   (OFF_XBF + SZ_XBF)
#define SZ_WB     (3072UL*768*2)        // Wxb; REUSED as per-t flags
#define OFF_WHB   (OFF_WXB + SZ_WB)
#define OFF_BALL  (OFF_WHB + SZ_WB)
#define SZ_BALL   (3072UL*4)
#define OFF_XG    (OFF_BALL + SZ_BALL)
#define SZ_XG     (512UL*3072*64*2)
#define OFF_END   (OFF_XG + SZ_XG)

// per-t h buffer: 64x768 bf16 = 98304 B; 512 of them = SZ_XBF exactly.
#define HSTRIDE   49152               // shorts per h buffer
// per-t flags: 96 x 64B = 6144 B (1536 ints); 512 steps = 3.1 MB < SZ_WB.
#define FSTRIDE   1536                // ints per step

__device__ __forceinline__ float bf2f(unsigned short u){
  union{unsigned int i; float f;} v; v.i = ((unsigned int)u)<<16; return v.f;
}
__device__ __forceinline__ unsigned short f2bf(float f){
  union{float f; unsigned int i;} v; v.f = f;
  unsigned int x = v.i;
  return (unsigned short)((x + 0x7fffu + ((x>>16)&1u)) >> 16);
}
__device__ __forceinline__ float sigm(float x){ return 1.0f/(1.0f + __expf(-x)); }
// overflow-safe tanh
__device__ __forceinline__ float tanh_s(float x){
  float e = __expf(2.0f*fabsf(x));
  float r = 1.0f - 2.0f/(e+1.0f);
  return copysignf(r, x);
}
__device__ __forceinline__ f32x4 mfma16(short8 a, short8 b, f32x4 c){
  return __builtin_amdgcn_mfma_f32_16x16x32_bf16(a, b, c, 0, 0, 0);
}
// h producer stores bypass L1+L2 (reach the memory-side coherence point, no
// dirty local-L2 copies). Readers use PLAIN cached loads on per-t addresses:
// never-reused addresses can't be stale in any cache. (Rounds 8/16, PASSED.)
__device__ __forceinline__ void st_b128_sc(unsigned short* p, short8 v){
  asm volatile("global_store_dwordx4 %0, %1, off sc0 sc1"
               :: "v"(p), "v"(v) : "memory");
}

// ---- converters ----
__global__ void k_conv_x(const float* __restrict__ x, unsigned short* __restrict__ xb, int n4){
  int i = blockIdx.x*blockDim.x + threadIdx.x;
  if (i >= n4) return;
  float4 v = ((const float4*)x)[i];
  u16x4 o = { f2bf(v.x), f2bf(v.y), f2bf(v.z), f2bf(v.w) };
  *(u16x4*)(xb + (size_t)i*4) = o;
}

__global__ void k_conv_w(const float* __restrict__ Wf, const float* __restrict__ Wi,
                         const float* __restrict__ Wg, const float* __restrict__ Wo,
                         unsigned short* __restrict__ Wxb, unsigned short* __restrict__ Whb){
  int i = blockIdx.x*blockDim.x + threadIdx.x;
  if (i >= 3072*192) return;
  int gj = i / 192; int kc = (i % 192)*4;
  int g = gj / 768, j = gj % 768;
  const float* W = (g==0)?Wf:(g==1)?Wi:(g==2)?Wg:Wo;
  float4 vx = *(const float4*)(W + (size_t)j*1536 + kc);
  float4 vh = *(const float4*)(W + (size_t)j*1536 + 768 + kc);
  u16x4 ox = {f2bf(vx.x),f2bf(vx.y),f2bf(vx.z),f2bf(vx.w)};
  u16x4 oh = {f2bf(vh.x),f2bf(vh.y),f2bf(vh.z),f2bf(vh.w)};
  *(u16x4*)(Wxb + (size_t)gj*768 + kc) = ox;
  *(u16x4*)(Whb + (size_t)gj*768 + kc) = oh;
}

__global__ void k_conv_b(const float* __restrict__ b0, const float* __restrict__ b1,
                         const float* __restrict__ b2, const float* __restrict__ b3,
                         float* __restrict__ ball){
  int i = blockIdx.x*blockDim.x + threadIdx.x;
  if (i >= 3072) return;
  int g = i/768, j = i%768;
  const float* b = (g==0)?b0:(g==1)?b1:(g==2)?b2:b3;
  ball[i] = b[j];
}

// ---- phase 1: Xg[t][gj][b] = (x @ Wx^T) + bias  (bias folded in) ----
__global__ __launch_bounds__(256) void k_gemm_x(const unsigned short* __restrict__ xb,
        const unsigned short* __restrict__ Wxb, const float* __restrict__ ball,
        unsigned short* __restrict__ Xg){
  __shared__ __align__(16) short Ald[128*32];
  __shared__ __align__(16) short Bld[128*32];
  int blk = blockIdx.x;
  int bm = blk / 24, bn = blk % 24;
  size_t Mbase = (size_t)bm*128; int Nbase = bn*128;
  int tid = threadIdx.x; int w = tid>>6, l = tid&63;
  int wm = w&1, wn = w>>1, lr = l&15, lg = l>>4;
  f32x4 acc[4][4];
  #pragma unroll
  for (int a=0;a<4;++a)
    #pragma unroll
    for(int b2=0;b2<4;++b2) acc[a][b2] = (f32x4){0.f,0.f,0.f,0.f};
  int c0i = tid, c1i = tid+256;
  int r0 = c0i>>2, o0 = (c0i&3)*8;
  int r1 = c1i>>2, o1 = (c1i&3)*8;
  for (int kt=0; kt<24; ++kt) {
    int k0 = kt*32;
    short8 a0 = *(const short8*)(xb + (Mbase + r0)*768 + k0 + o0);
    short8 a1 = *(const short8*)(xb + (Mbase + r1)*768 + k0 + o1);
    short8 b0 = *(const short8*)(Wxb + (size_t)(Nbase + r0)*768 + k0 + o0);
    short8 b1 = *(const short8*)(Wxb + (size_t)(Nbase + r1)*768 + k0 + o1);
    __syncthreads();
    *(short8*)(Ald + r0*32 + o0) = a0;
    *(short8*)(Ald + r1*32 + o1) = a1;
    *(short8*)(Bld + r0*32 + o0) = b0;
    *(short8*)(Bld + r1*32 + o1) = b1;
    __syncthreads();
    short8 af[4], bfr[4];
    #pragma unroll
    for (int mi=0;mi<4;++mi) af[mi] = *(const short8*)(Ald + (wm*64+mi*16+lr)*32 + lg*8);
    #pragma unroll
    for (int ni=0;ni<4;++ni) bfr[ni] = *(const short8*)(Bld + (wn*64+ni*16+lr)*32 + lg*8);
    #pragma unroll
    for (int mi=0;mi<4;++mi)
      #pragma unroll
      for (int ni=0;ni<4;++ni)
        acc[mi][ni] = mfma16(af[mi], bfr[ni], acc[mi][ni]);
  }
  float bs[4];
  #pragma unroll
  for (int ni=0;ni<4;++ni) bs[ni] = ball[Nbase + wn*64 + ni*16 + lr];
  #pragma unroll
  for (int mi=0;mi<4;++mi){
    int m0 = (int)Mbase + wm*64 + mi*16 + lg*4;
    int t = m0>>6, b = m0&63;
    #pragma unroll
    for (int ni=0;ni<4;++ni){
      int col = Nbase + wn*64 + ni*16 + lr;
      u16x4 u = { f2bf(acc[mi][ni][0]+bs[ni]), f2bf(acc[mi][ni][1]+bs[ni]),
                  f2bf(acc[mi][ni][2]+bs[ni]), f2bf(acc[mi][ni][3]+bs[ni]) };
      *(u16x4*)(Xg + ((size_t)t*3072 + col)*64 + b) = u;
    }
  }
}

// ---- phase 2: persistent recurrent kernel (ROUND-16 base, two deltas):
// (1) A-loads issued BEFORE the deferred out stores (vmcnt retires in
//     order; stores must sit YOUNGER so MFMA's load-wait skips store acks);
// (2) sticky-done poll: each lane stops re-loading its flag once seen ->
//     poll fabric traffic decays instead of hammering straggler lines.
__global__ __launch_bounds__(512, 1) void k_lstm(const unsigned short* __restrict__ Xg,
     const unsigned short* __restrict__ Whb,
     unsigned short* __restrict__ hbase, float* __restrict__ out,
     int* __restrict__ flags){
  __shared__ __align__(16) short Wl[32*776];          // Wh slice (2-way bank alias only)
  __shared__ __align__(16) unsigned short hl[64*8];   // h pack tile
  int s = blockIdx.x, tid = threadIdx.x;
  int w8 = tid>>6, l = tid&63;
  int m = w8 & 3, nh = w8 >> 2;
  int n0 = l & 15, lg = l >> 4;
  int gate = n0 >> 2;
  int jj4 = nh*4 + (n0 & 3);
  int j = s*8 + jj4;
  size_t gj = (size_t)gate*768 + j;
  int rB = jj4*4 + gate;

  // stage Wh slice once: Wl[rB][k] = Whb[gate*768 + s*8 + jj][k]
  for (int c = tid; c < 3072; c += 512){
    int r = c/96, off = (c%96)*8;
    int gt = r & 3, jq = r >> 2;
    short8 v = *(const short8*)(Whb + ((size_t)(gt*768 + s*8 + jq))*768 + off);
    *(short8*)(Wl + r*776 + off) = v;
  }
  __syncthreads();

  float cst[4] = {0.f, 0.f, 0.f, 0.f};
  int arow = m*16 + n0;
  int b4 = m*16 + lg*4;
  bool actv = (n0 < 4);
  u16x4 xg = *(const u16x4*)(Xg + gj*64 + b4);   // t=0 prefetch
  float pend[4];                                  // deferred out values

  for (int t=0; t<512; ++t){
    const unsigned short* hb = hbase + (size_t)t*HSTRIDE;
    unsigned short* hn = hbase + (size_t)(t+1)*HSTRIDE;
    // A-fragments FIRST (plain cached loads on fresh per-t addresses)
    short8 afr[24];
    #pragma unroll
    for (int kk=0; kk<24; ++kk)
      afr[kk] = *(const short8*)(hb + arow*768 + kk*32 + lg*8);
    // deferred out stores for t-1: issued AFTER the A-loads so they sit
    // younger in the in-order vmcnt queue (don't gate the MFMA's wait)
    if (t > 0 && actv){
      #pragma unroll
      for (int r=0;r<4;++r)
        out[((size_t)(t-1)*64 + b4 + r)*768 + j] = pend[r];
    }
    // MFMA with B from LDS; two acc chains for latency
    f32x4 acc0 = {0.f,0.f,0.f,0.f}, acc1 = {0.f,0.f,0.f,0.f};
    #pragma unroll
    for (int kk=0; kk<24; kk+=2){
      short8 b0 = *(const short8*)(Wl + rB*776 + kk*32 + lg*8);
      short8 b1 = *(const short8*)(Wl + rB*776 + (kk+1)*32 + lg*8);
      acc0 = mfma16(afr[kk],   b0, acc0);
      acc1 = mfma16(afr[kk+1], b1, acc1);
    }
    f32x4 acc = acc0 + acc1;
    // pre-activation (bias already folded into Xg) + gate nonlinearity
    float av[4];
    #pragma unroll
    for (int r=0; r<4; ++r){
      float pre = acc[r] + bf2f(xg[r]);
      av[r] = (gate == 2) ? tanh_s(pre) : sigm(pre);
    }
    // gather i (xor4), g (xor8), o (xor12); f lane-local for n0<4
    #pragma unroll
    for (int r=0; r<4; ++r){
      float iv = __shfl_xor(av[r], 4);
      float gv = __shfl_xor(av[r], 8);
      float ov = __shfl_xor(av[r], 12);
      float cn = av[r]*cst[r] + iv*gv;
      float hv = ov * tanh_s(cn);
      if (actv){
        cst[r] = cn;
        pend[r] = hv;
        hl[(b4 + r)*8 + jj4] = f2bf(hv);   // pack tile
      }
    }
    if (t < 511){
      __syncthreads();                   // hl complete
      if (w8 == 7){
        // 64 coalesced 16B h-stores to h[t+1]; only these gate the flag
        short8 hp = *(const short8*)(hl + l*8);
        st_b128_sc(hn + (size_t)l*768 + s*8, hp);
        asm volatile("s_waitcnt vmcnt(0)" ::: "memory");
        if (l == 0)
          __hip_atomic_store(&flags[(size_t)t*FSTRIDE + s*16], 1,
                             __ATOMIC_RELAXED, __HIP_MEMORY_SCOPE_AGENT);
      }
      u16x4 xgn = *(const u16x4*)(Xg + ((size_t)(t+1)*3072 + gj)*64 + b4);
      if (w8 == 0){
        const int* fl = flags + (size_t)t*FSTRIDE;
        // sticky-done bounded poll (wave 0 only): a lane stops loading its
        // flag once seen -> traffic decays to just the stragglers' lines
        bool d1 = false, d2 = (l >= 32);
        for (int it=0; it<(1<<15); ++it){
          if (!d1)
            d1 = 0 != __hip_atomic_load(&fl[l*16], __ATOMIC_RELAXED, __HIP_MEMORY_SCOPE_AGENT);
          if (!d2)
            d2 = 0 != __hip_atomic_load(&fl[(64+l)*16], __ATOMIC_RELAXED, __HIP_MEMORY_SCOPE_AGENT);
          if (__all(d1 && d2)) break;
        }
      }
      __syncthreads();                   // release: all 96 flags set for t
      xg = xgn;
    }
  }
  // final stores: out[511] + hT + cT
  if (actv){
    #pragma unroll
    for (int r=0; r<4; ++r){
      int b = b4 + r;
      out[((size_t)511*64 + b)*768 + j] = pend[r];
      out[(512UL*64 + b)*768 + j] = pend[r];      // hT
      out[(512UL*64 + 64 + b)*768 + j] = cst[r];  // cT
    }
  }
}

extern "C" void kernel_launch(void* const* d_in, const int* in_sizes, int n_in,
                              void* d_out, int out_size, void* d_ws, size_t ws_size,
                              hipStream_t stream){
  const float* x   = (const float*)d_in[0];
  const float* Wf  = (const float*)d_in[1];
  const float* bf_ = (const float*)d_in[2];
  const float* Wi  = (const float*)d_in[3];
  const float* bi_ = (const float*)d_in[4];
  const float* Wg  = (const float*)d_in[5];
  const float* bg_ = (const float*)d_in[6];
  const float* Wo  = (const float*)d_in[7];
  const float* bo_ = (const float*)d_in[8];
  char* ws = (char*)d_ws;
  if (ws_size < OFF_END) return;  // need ~252 MB scratch
  unsigned short* xb   = (unsigned short*)(ws + OFF_XBF);   // then: per-t h buffers
  unsigned short* Wxb  = (unsigned short*)(ws + OFF_WXB);   // then: per-t flags
  unsigned short* Whb  = (unsigned short*)(ws + OFF_WHB);
  float*          ball = (float*)(ws + OFF_BALL);
  unsigned short* Xg   = (unsigned short*)(ws + OFF_XG);
  float* out = (float*)d_out;

  k_conv_x<<<24576, 256, 0, stream>>>(x, xb, 6291456);
  k_conv_w<<<2304, 256, 0, stream>>>(Wf, Wi, Wg, Wo, Wxb, Whb);
  k_conv_b<<<12, 256, 0, stream>>>(bf_, bi_, bg_, bo_, ball);
  k_gemm_x<<<6144, 256, 0, stream>>>(xb, Wxb, ball, Xg);
  // xb/Wxb are dead now; reuse as per-t h buffers (h0=0) and per-t flags=0.
  // (MUST be after k_gemm_x in stream order; reset every call for replays.)
  (void)hipMemsetAsync(ws + OFF_XBF, 0, 98304, stream);            // h[0] = 0
  (void)hipMemsetAsync(ws + OFF_WXB, 0, 512UL*FSTRIDE*4, stream);  // flags = 0
  k_lstm<<<NWG, 512, 0, stream>>>(Xg, Whb,
                                  (unsigned short*)(ws + OFF_XBF), out,
                                  (int*)(ws + OFF_WXB));
}